// Round 2
// baseline (1614.938 us; speedup 1.0000x reference)
//
#include <hip/hip_runtime.h>
#include <cstddef>

#define TC 96          // channels
#define NT 256         // threads per block
#define EBM 128        // edges per tile (800000 % 128 == 0)
#define AST 104        // A lds row stride in bf16 (208 B: 16B-aligned, ~2-way banks)
#define WST 196        // W stage row stride in floats (784 B, 16B-aligned)
#define BM 64          // node kernel rows per tile
#define XST 204
#define HST 100

typedef __bf16 bf16x8 __attribute__((ext_vector_type(8)));
typedef __bf16 bf16x4 __attribute__((ext_vector_type(4)));
typedef float  f32x4  __attribute__((ext_vector_type(4)));

__device__ __forceinline__ float fsigmoid(float x) {
    return 1.0f / (1.0f + __expf(-x));
}

// ---------------------------------------------------------------------------
// Edge kernel (MFMA split-bf16).
// Persistent blocks; per block: stage Wcat=[Wa1|Wx1] (96x192 fp32) in LDS once,
// extract per-wave B fragments (hi/lo bf16) to registers, then grid-stride over
// 128-edge tiles: stage m as split bf16 in LDS, 16x16x32 MFMA (hh+lh+hl),
// fused SiLU+W2 epilogue, atomic scatter (unchanged semantics).
// Wave w owns output cols [w*48, w*48+48): waves 0,1 = attention, 2,3 = phi_x.
// ---------------------------------------------------------------------------
__global__ __launch_bounds__(NT, 2)
void edge_kernel(const float* __restrict__ m_ji,
                 const int*   __restrict__ edge_idx,   // [2][E]
                 const float* __restrict__ coords,
                 const float* __restrict__ Wa1, const float* __restrict__ ba1,
                 const float* __restrict__ Wa2, const float* __restrict__ ba2,
                 const float* __restrict__ Wx1, const float* __restrict__ bx1,
                 const float* __restrict__ Wx2, const float* __restrict__ bx2,
                 float* __restrict__ m_acc,
                 float* __restrict__ out_coords,
                 float* __restrict__ out_att,
                 int E, int ntiles)
{
    // LDS: W-stage (75264 B) reused as A hi/lo (53248 B) after frag extraction
    __shared__ __align__(16) unsigned char s_buf[96 * WST * 4];
    __shared__ float s_red[4][EBM];
    __shared__ float s_att[EBM];
    __shared__ float s_phx[EBM];
    __shared__ int   s_recv[EBM];
    __shared__ int   s_send[EBM];

    float*  Wst = (float*)s_buf;                       // [96][WST]
    __bf16* Ahi = (__bf16*)s_buf;                      // [EBM][AST]
    __bf16* Alo = (__bf16*)(s_buf + EBM * AST * 2);    // [EBM][AST]

    const int tid  = threadIdx.x;
    const int lane = tid & 63;
    const int wave = tid >> 6;
    const int lr   = lane & 15;   // col-in-16 (B/C) / row-in-16 (A)
    const int lq   = lane >> 4;   // quadrant

    // ---- stage Wcat fp32 into LDS (one-time) ----
    for (int i = tid; i < 96 * 48; i += NT) {
        const int k  = i / 48;
        const int c4 = i % 48;
        const float* src = (c4 < 24) ? (Wa1 + (size_t)k * TC + c4 * 4)
                                     : (Wx1 + (size_t)k * TC + (c4 - 24) * 4);
        const float4 v = *reinterpret_cast<const float4*>(src);
        *reinterpret_cast<float4*>(&Wst[k * WST + c4 * 4]) = v;
    }
    __syncthreads();

    // ---- extract B fragments (hi/lo) to registers ----
    // B frag for n-tile nt, k-chunk c: lane holds col n = wave*48 + nt*16 + lr,
    // k = c*32 + lq*8 + j  (j = 0..7, contiguous)
    bf16x8 BH[3][3], BL[3][3];
    #pragma unroll
    for (int nt = 0; nt < 3; ++nt) {
        const int n = wave * 48 + nt * 16 + lr;
        #pragma unroll
        for (int c = 0; c < 3; ++c) {
            #pragma unroll
            for (int j = 0; j < 8; ++j) {
                const int k = c * 32 + lq * 8 + j;
                const float w = Wst[k * WST + n];
                const __bf16 h = (__bf16)w;
                BH[nt][c][j] = h;
                BL[nt][c][j] = (__bf16)(w - (float)h);
            }
        }
    }
    // per-thread bias + layer-2 weight for owned cols
    const bool isAtt = (wave < 2);
    const float* b1src = isAtt ? ba1 : bx1;
    const float* w2src = isAtt ? Wa2 : Wx2;
    float b1v[3], w2v[3];
    #pragma unroll
    for (int nt = 0; nt < 3; ++nt) {
        const int nl = (wave & 1) * 48 + nt * 16 + lr;  // col within its matrix
        b1v[nt] = b1src[nl];
        w2v[nt] = w2src[nl];
    }
    const float ba2v = ba2[0];
    const float bx2v = bx2[0];

    // ---- grid-stride over edge tiles ----
    for (int tile = blockIdx.x; tile < ntiles; tile += gridDim.x) {
        const int e0   = tile * EBM;
        const int rows = (E - e0 < EBM) ? (E - e0) : EBM;

        __syncthreads();  // previous tile's scatter reads of A/s_att done

        if (tid < EBM) {
            const int e = (tid < rows) ? (e0 + tid) : (E - 1);
            s_recv[tid] = edge_idx[e];
            s_send[tid] = edge_idx[E + e];
        }
        // stage m tile as split bf16
        for (int i = tid; i < EBM * 24; i += NT) {
            const int r  = i / 24;
            const int c4 = i % 24;
            const int e  = (r < rows) ? (e0 + r) : (E - 1);
            const float4 v = *reinterpret_cast<const float4*>(&m_ji[(size_t)e * TC + c4 * 4]);
            bf16x4 hv, lv;
            const float vv[4] = {v.x, v.y, v.z, v.w};
            #pragma unroll
            for (int j = 0; j < 4; ++j) {
                const __bf16 h = (__bf16)vv[j];
                hv[j] = h;
                lv[j] = (__bf16)(vv[j] - (float)h);
            }
            *reinterpret_cast<bf16x4*>(&Ahi[r * AST + c4 * 4]) = hv;
            *reinterpret_cast<bf16x4*>(&Alo[r * AST + c4 * 4]) = lv;
        }
        __syncthreads();

        // ---- MFMA main: 8 m-tiles in pairs, 3 n-tiles, 3 k-chunks, 3 products
        #pragma unroll
        for (int mp = 0; mp < 4; ++mp) {
            f32x4 acc[2][3];
            #pragma unroll
            for (int s = 0; s < 2; ++s)
                #pragma unroll
                for (int nt = 0; nt < 3; ++nt)
                    acc[s][nt] = (f32x4){0.f, 0.f, 0.f, 0.f};

            #pragma unroll
            for (int c = 0; c < 3; ++c) {
                const int koff = c * 32 + lq * 8;
                const int row0 = (mp * 2 + 0) * 16 + lr;
                const int row1 = (mp * 2 + 1) * 16 + lr;
                const bf16x8 aH0 = *reinterpret_cast<const bf16x8*>(&Ahi[row0 * AST + koff]);
                const bf16x8 aL0 = *reinterpret_cast<const bf16x8*>(&Alo[row0 * AST + koff]);
                const bf16x8 aH1 = *reinterpret_cast<const bf16x8*>(&Ahi[row1 * AST + koff]);
                const bf16x8 aL1 = *reinterpret_cast<const bf16x8*>(&Alo[row1 * AST + koff]);
                #pragma unroll
                for (int nt = 0; nt < 3; ++nt) {
                    acc[0][nt] = __builtin_amdgcn_mfma_f32_16x16x32_bf16(aH0, BH[nt][c], acc[0][nt], 0, 0, 0);
                    acc[1][nt] = __builtin_amdgcn_mfma_f32_16x16x32_bf16(aH1, BH[nt][c], acc[1][nt], 0, 0, 0);
                    acc[0][nt] = __builtin_amdgcn_mfma_f32_16x16x32_bf16(aL0, BH[nt][c], acc[0][nt], 0, 0, 0);
                    acc[1][nt] = __builtin_amdgcn_mfma_f32_16x16x32_bf16(aL1, BH[nt][c], acc[1][nt], 0, 0, 0);
                    acc[0][nt] = __builtin_amdgcn_mfma_f32_16x16x32_bf16(aH0, BL[nt][c], acc[0][nt], 0, 0, 0);
                    acc[1][nt] = __builtin_amdgcn_mfma_f32_16x16x32_bf16(aH1, BL[nt][c], acc[1][nt], 0, 0, 0);
                }
            }

            // epilogue: bias + SiLU + dot(W2) + 16-lane reduce
            #pragma unroll
            for (int s = 0; s < 2; ++s) {
                float p[4] = {0.f, 0.f, 0.f, 0.f};
                #pragma unroll
                for (int nt = 0; nt < 3; ++nt) {
                    #pragma unroll
                    for (int q = 0; q < 4; ++q) {
                        const float h = acc[s][nt][q] + b1v[nt];
                        p[q] = fmaf(h * fsigmoid(h), w2v[nt], p[q]);
                    }
                }
                #pragma unroll
                for (int m = 1; m <= 8; m <<= 1) {
                    #pragma unroll
                    for (int q = 0; q < 4; ++q) p[q] += __shfl_xor(p[q], m, 64);
                }
                if (lr == 0) {
                    const int rbase = (mp * 2 + s) * 16 + lq * 4;
                    #pragma unroll
                    for (int q = 0; q < 4; ++q) s_red[wave][rbase + q] = p[q];
                }
            }
        }
        __syncthreads();

        if (tid < EBM) {
            const float sa = s_red[0][tid] + s_red[1][tid] + ba2v;
            const float sx = s_red[2][tid] + s_red[3][tid] + bx2v;
            const float att = fsigmoid(sa);
            s_att[tid] = att;
            s_phx[tid] = sx;
            if (tid < rows) out_att[e0 + tid] = att;
        }
        __syncthreads();

        // scatter attention-weighted messages (reconstruct m = hi+lo)
        for (int i = tid; i < rows * 24; i += NT) {
            const int r  = i / 24;
            const int c4 = (i % 24) * 4;
            const bf16x4 hv = *reinterpret_cast<const bf16x4*>(&Ahi[r * AST + c4]);
            const bf16x4 lv = *reinterpret_cast<const bf16x4*>(&Alo[r * AST + c4]);
            const float a = s_att[r];
            float* dst = &m_acc[(size_t)s_recv[r] * TC + c4];
            #pragma unroll
            for (int j = 0; j < 4; ++j) {
                atomicAdd(dst + j, a * ((float)hv[j] + (float)lv[j]));
            }
        }
        // coordinate deltas
        if (tid < rows) {
            const int rcv = s_recv[tid];
            const int snd = s_send[tid];
            const float dx = coords[snd * 3 + 0] - coords[rcv * 3 + 0];
            const float dy = coords[snd * 3 + 1] - coords[rcv * 3 + 1];
            const float dz = coords[snd * 3 + 2] - coords[rcv * 3 + 2];
            const float nr = sqrtf(dx * dx + dy * dy + dz * dz);
            const float f  = s_phx[tid] / (nr + 1.0f);
            atomicAdd(&out_coords[rcv * 3 + 0], dx * f);
            atomicAdd(&out_coords[rcv * 3 + 1], dy * f);
            atomicAdd(&out_coords[rcv * 3 + 2], dz * f);
        }
    }
}

// ---------------------------------------------------------------------------
// Node kernel: unchanged from round 1 (next-round target).
// ---------------------------------------------------------------------------
__global__ __launch_bounds__(NT, 2)
void node_kernel(const float* __restrict__ node_feats,
                 const float* __restrict__ m_acc,
                 const float* __restrict__ Wn1, const float* __restrict__ bn1,
                 const float* __restrict__ Wn2, const float* __restrict__ bn2,
                 float* __restrict__ out_nf,
                 int N)
{
    __shared__ float X[BM][XST];
    __shared__ float H[BM][HST];

    const int tid = threadIdx.x;
    const int n0  = blockIdx.x * BM;

    for (int i4 = tid; i4 < BM * 48; i4 += NT) {
        const int r  = i4 / 48;
        const int c4 = i4 % 48;
        int node = n0 + r;
        if (node >= N) node = N - 1;
        float4 v;
        if (c4 < 24) v = *reinterpret_cast<const float4*>(node_feats + (size_t)node * TC + c4 * 4);
        else         v = *reinterpret_cast<const float4*>(m_acc + (size_t)node * TC + (c4 - 24) * 4);
        *reinterpret_cast<float4*>(&X[r][c4 * 4]) = v;
    }
    __syncthreads();

    const int tx = tid & 15;
    const int ty = tid >> 4;
    const int r0 = ty * 4;
    const int c0 = tx * 6;

    float acc[4][6];
    #pragma unroll
    for (int q = 0; q < 4; ++q) {
        #pragma unroll
        for (int j = 0; j < 6; ++j) acc[q][j] = 0.0f;
    }
    #pragma unroll 2
    for (int k = 0; k < 2 * TC; ++k) {
        const float2 b0 = *reinterpret_cast<const float2*>(Wn1 + (size_t)k * TC + c0 + 0);
        const float2 b1 = *reinterpret_cast<const float2*>(Wn1 + (size_t)k * TC + c0 + 2);
        const float2 b2 = *reinterpret_cast<const float2*>(Wn1 + (size_t)k * TC + c0 + 4);
        const float bv[6] = {b0.x, b0.y, b1.x, b1.y, b2.x, b2.y};
        const float a0 = X[r0 + 0][k];
        const float a1 = X[r0 + 1][k];
        const float a2 = X[r0 + 2][k];
        const float a3 = X[r0 + 3][k];
        #pragma unroll
        for (int j = 0; j < 6; ++j) {
            acc[0][j] = fmaf(a0, bv[j], acc[0][j]);
            acc[1][j] = fmaf(a1, bv[j], acc[1][j]);
            acc[2][j] = fmaf(a2, bv[j], acc[2][j]);
            acc[3][j] = fmaf(a3, bv[j], acc[3][j]);
        }
    }
    {
        float bnv[6];
        #pragma unroll
        for (int j = 0; j < 6; ++j) bnv[j] = bn1[c0 + j];
        #pragma unroll
        for (int q = 0; q < 4; ++q) {
            #pragma unroll
            for (int j = 0; j < 6; ++j) {
                const float h = acc[q][j] + bnv[j];
                H[r0 + q][c0 + j] = h * fsigmoid(h);
            }
        }
    }
    __syncthreads();

    float acc2[4][6];
    #pragma unroll
    for (int q = 0; q < 4; ++q) {
        #pragma unroll
        for (int j = 0; j < 6; ++j) acc2[q][j] = 0.0f;
    }
    #pragma unroll 2
    for (int k = 0; k < TC; ++k) {
        const float2 b0 = *reinterpret_cast<const float2*>(Wn2 + (size_t)k * TC + c0 + 0);
        const float2 b1 = *reinterpret_cast<const float2*>(Wn2 + (size_t)k * TC + c0 + 2);
        const float2 b2 = *reinterpret_cast<const float2*>(Wn2 + (size_t)k * TC + c0 + 4);
        const float bv[6] = {b0.x, b0.y, b1.x, b1.y, b2.x, b2.y};
        const float a0 = H[r0 + 0][k];
        const float a1 = H[r0 + 1][k];
        const float a2 = H[r0 + 2][k];
        const float a3 = H[r0 + 3][k];
        #pragma unroll
        for (int j = 0; j < 6; ++j) {
            acc2[0][j] = fmaf(a0, bv[j], acc2[0][j]);
            acc2[1][j] = fmaf(a1, bv[j], acc2[1][j]);
            acc2[2][j] = fmaf(a2, bv[j], acc2[2][j]);
            acc2[3][j] = fmaf(a3, bv[j], acc2[3][j]);
        }
    }
    {
        float bnv[6];
        #pragma unroll
        for (int j = 0; j < 6; ++j) bnv[j] = bn2[c0 + j];
        #pragma unroll
        for (int q = 0; q < 4; ++q) {
            const int node = n0 + r0 + q;
            if (node < N) {
                #pragma unroll
                for (int j = 0; j < 6; ++j) {
                    out_nf[(size_t)node * TC + c0 + j] = acc2[q][j] + bnv[j] + X[r0 + q][c0 + j];
                }
            }
        }
    }
}

extern "C" void kernel_launch(void* const* d_in, const int* in_sizes, int n_in,
                              void* d_out, int out_size, void* d_ws, size_t ws_size,
                              hipStream_t stream)
{
    const float* node_feats = (const float*)d_in[0];
    const float* coords     = (const float*)d_in[1];
    const float* m_ji       = (const float*)d_in[2];
    const int*   edge_idx   = (const int*)  d_in[3];
    const float* Wn1 = (const float*)d_in[4];
    const float* bn1 = (const float*)d_in[5];
    const float* Wn2 = (const float*)d_in[6];
    const float* bn2 = (const float*)d_in[7];
    const float* Wa1 = (const float*)d_in[8];
    const float* ba1 = (const float*)d_in[9];
    const float* Wa2 = (const float*)d_in[10];
    const float* ba2 = (const float*)d_in[11];
    const float* Wx1 = (const float*)d_in[12];
    const float* bx1 = (const float*)d_in[13];
    const float* Wx2 = (const float*)d_in[14];
    const float* bx2 = (const float*)d_in[15];

    const int N = in_sizes[0] / TC;
    const int E = in_sizes[2] / TC;

    float* out_nf     = (float*)d_out;
    float* out_coords = out_nf + (size_t)N * TC;
    float* out_att    = out_coords + (size_t)N * 3;
    float* m_acc      = (float*)d_ws;

    hipMemsetAsync(m_acc, 0, (size_t)N * TC * sizeof(float), stream);
    hipMemcpyAsync(out_coords, coords, (size_t)N * 3 * sizeof(float),
                   hipMemcpyDeviceToDevice, stream);

    const int ntiles = (E + EBM - 1) / EBM;
    const int edge_blocks = 512;   // 2 per CU (LDS-capped), persistent
    edge_kernel<<<edge_blocks, NT, 0, stream>>>(
        m_ji, edge_idx, coords,
        Wa1, ba1, Wa2, ba2, Wx1, bx1, Wx2, bx2,
        m_acc, out_coords, out_att, E, ntiles);

    const int node_blocks = (N + BM - 1) / BM;
    node_kernel<<<node_blocks, NT, 0, stream>>>(
        node_feats, m_acc, Wn1, bn1, Wn2, bn2, out_nf, N);
}

// Round 5
// 938.636 us; speedup vs baseline: 1.7205x; 1.7205x over previous
//
#include <hip/hip_runtime.h>
#include <cstddef>

#define TC 96          // channels
#define NT 256         // threads per block
#define EBM 64         // edges per tile (800000 % 64 == 0)
#define AST 104        // edge A lds row stride in bf16 (208 B)
#define HLD 100        // node H lds row stride in floats (<=2-way banks)

typedef __bf16 bf16x8 __attribute__((ext_vector_type(8)));
typedef __bf16 bf16x4 __attribute__((ext_vector_type(4)));
typedef float  f32x4  __attribute__((ext_vector_type(4)));

__device__ __forceinline__ float fsigmoid(float x) {
    return 1.0f / (1.0f + __expf(-x));
}

// ---------------------------------------------------------------------------
// CSR build: histogram -> scan -> fill  (receiver-sorted edge permutation)
// ---------------------------------------------------------------------------
__global__ void hist_kernel(const int* __restrict__ recv, int* __restrict__ count, int E) {
    const int e = blockIdx.x * blockDim.x + threadIdx.x;
    if (e < E) atomicAdd(&count[recv[e]], 1);
}

__global__ void scan_kernel(const int* __restrict__ count, int* __restrict__ offsets,
                            int* __restrict__ cursor, int N, int E) {
    __shared__ int partial[1024];
    const int tid = threadIdx.x;
    const int chunk = (N + 1023) / 1024;
    const int a = tid * chunk;
    const int b = (a + chunk < N) ? (a + chunk) : N;
    int s = 0;
    for (int i = a; i < b; ++i) s += count[i];
    partial[tid] = s;
    __syncthreads();
    for (int d = 1; d < 1024; d <<= 1) {
        const int v = (tid >= d) ? partial[tid - d] : 0;
        __syncthreads();
        partial[tid] += v;
        __syncthreads();
    }
    int run = partial[tid] - s;   // exclusive prefix at chunk start
    for (int i = a; i < b; ++i) {
        offsets[i] = run;
        cursor[i]  = run;
        run += count[i];
    }
    if (tid == 1023) offsets[N] = E;
}

__global__ void fill_kernel(const int* __restrict__ recv, int* __restrict__ cursor,
                            int* __restrict__ eperm, int E) {
    const int e = blockIdx.x * blockDim.x + threadIdx.x;
    if (e < E) {
        const int pos = atomicAdd(&cursor[recv[e]], 1);
        eperm[pos] = e;
    }
}

// ---------------------------------------------------------------------------
// Weight prep: pack Wn1/Wn2 as split-bf16 hi/lo in MFMA fragment order.
// Fragment (nt, c): element j of lane (lq*16+lr) is W[k= c*32+lq*8+j][n= nt*16+lr].
// Stored lane-contiguous: frag_base = (g*64 + lane)*8  ->  16B dwordx4 per lane.
// ---------------------------------------------------------------------------
__global__ void wprep_kernel(const float* __restrict__ Wn1, const float* __restrict__ Wn2,
                             __bf16* __restrict__ B1H, __bf16* __restrict__ B1L,
                             __bf16* __restrict__ B2H, __bf16* __restrict__ B2L)
{
    const int t = blockIdx.x * blockDim.x + threadIdx.x;
    if (t < 36 * 64) {                       // Wn1: nt 0..5, c 0..5
        const int lane = t & 63;
        const int g    = t >> 6;             // nt*6 + c
        const int nt   = g / 6;
        const int c    = g - nt * 6;
        const int lr   = lane & 15;
        const int lq   = lane >> 4;
        const int n    = nt * 16 + lr;
        #pragma unroll
        for (int j = 0; j < 8; ++j) {
            const int k = c * 32 + lq * 8 + j;
            const float w = Wn1[(size_t)k * TC + n];
            const __bf16 h = (__bf16)w;
            B1H[(size_t)t * 8 + j] = h;
            B1L[(size_t)t * 8 + j] = (__bf16)(w - (float)h);
        }
    } else if (t < 36 * 64 + 18 * 64) {      // Wn2: nt 0..5, c 0..2
        const int t2   = t - 36 * 64;
        const int lane = t2 & 63;
        const int g    = t2 >> 6;            // nt*3 + c
        const int nt   = g / 3;
        const int c    = g - nt * 3;
        const int lr   = lane & 15;
        const int lq   = lane >> 4;
        const int n    = nt * 16 + lr;
        #pragma unroll
        for (int j = 0; j < 8; ++j) {
            const int k = c * 32 + lq * 8 + j;
            const float w = Wn2[(size_t)k * TC + n];
            const __bf16 h = (__bf16)w;
            B2H[(size_t)t2 * 8 + j] = h;
            B2L[(size_t)t2 * 8 + j] = (__bf16)(w - (float)h);
        }
    }
}

// ---------------------------------------------------------------------------
// Edge kernel (MFMA split-bf16): attention + phi_x scalars only.
// (unchanged from round 3 — design under test)
// ---------------------------------------------------------------------------
__global__ __launch_bounds__(NT, 4)
void edge_kernel(const float* __restrict__ m_ji,
                 const int*   __restrict__ edge_idx,   // [2][E]
                 const float* __restrict__ coords,
                 const float* __restrict__ Wa1, const float* __restrict__ ba1,
                 const float* __restrict__ Wa2, const float* __restrict__ ba2,
                 const float* __restrict__ Wx1, const float* __restrict__ bx1,
                 const float* __restrict__ Wx2, const float* __restrict__ bx2,
                 float* __restrict__ out_coords,
                 float* __restrict__ out_att,
                 int E, int ntiles)
{
    __shared__ __bf16 Ahi[EBM * AST];
    __shared__ __bf16 Alo[EBM * AST];
    __shared__ float  s_red[4][EBM];

    const int tid  = threadIdx.x;
    const int lane = tid & 63;
    const int wave = tid >> 6;
    const int lr   = lane & 15;
    const int lq   = lane >> 4;

    // ---- B fragment extraction (hi/lo) directly from global ----
    const bool isAtt = (wave < 2);
    const float* __restrict__ Wsrc  = isAtt ? Wa1 : Wx1;
    const float* __restrict__ b1src = isAtt ? ba1 : bx1;
    const float* __restrict__ w2src = isAtt ? Wa2 : Wx2;
    const int colbase = (wave & 1) * 48;

    bf16x8 BH[3][3], BL[3][3];
    float b1v[3], w2v[3];
    #pragma unroll
    for (int nt = 0; nt < 3; ++nt) {
        const int n = colbase + nt * 16 + lr;
        #pragma unroll
        for (int c = 0; c < 3; ++c) {
            #pragma unroll
            for (int j = 0; j < 8; ++j) {
                const int k = c * 32 + lq * 8 + j;
                const float w = Wsrc[(size_t)k * TC + n];
                const __bf16 h = (__bf16)w;
                BH[nt][c][j] = h;
                BL[nt][c][j] = (__bf16)(w - (float)h);
            }
        }
        b1v[nt] = b1src[n];
        w2v[nt] = w2src[n];
    }
    const float ba2v = ba2[0];
    const float bx2v = bx2[0];

    // ---- grid-stride over 64-edge tiles ----
    for (int tile = blockIdx.x; tile < ntiles; tile += gridDim.x) {
        const int e0   = tile * EBM;
        const int rows = (E - e0 < EBM) ? (E - e0) : EBM;

        __syncthreads();   // previous tile fully consumed

        // stage m tile as split bf16 (lane -> consecutive 16B, coalesced)
        for (int i = tid; i < EBM * 24; i += NT) {
            const int r  = i / 24;
            const int c4 = i % 24;
            const int e  = (r < rows) ? (e0 + r) : (E - 1);
            const float4 v = *reinterpret_cast<const float4*>(&m_ji[(size_t)e * TC + c4 * 4]);
            const float vv[4] = {v.x, v.y, v.z, v.w};
            bf16x4 hv, lv;
            #pragma unroll
            for (int j = 0; j < 4; ++j) {
                const __bf16 h = (__bf16)vv[j];
                hv[j] = h;
                lv[j] = (__bf16)(vv[j] - (float)h);
            }
            *reinterpret_cast<bf16x4*>(&Ahi[r * AST + c4 * 4]) = hv;
            *reinterpret_cast<bf16x4*>(&Alo[r * AST + c4 * 4]) = lv;
        }
        __syncthreads();

        // ---- MFMA: 4 m-tiles in 2 pairs, 3 n-tiles, 3 k-chunks, 3 products
        #pragma unroll
        for (int mp = 0; mp < 2; ++mp) {
            f32x4 acc[2][3];
            #pragma unroll
            for (int s = 0; s < 2; ++s)
                #pragma unroll
                for (int nt = 0; nt < 3; ++nt)
                    acc[s][nt] = (f32x4){0.f, 0.f, 0.f, 0.f};

            #pragma unroll
            for (int c = 0; c < 3; ++c) {
                const int koff = c * 32 + lq * 8;
                const int row0 = (mp * 2 + 0) * 16 + lr;
                const int row1 = (mp * 2 + 1) * 16 + lr;
                const bf16x8 aH0 = *reinterpret_cast<const bf16x8*>(&Ahi[row0 * AST + koff]);
                const bf16x8 aL0 = *reinterpret_cast<const bf16x8*>(&Alo[row0 * AST + koff]);
                const bf16x8 aH1 = *reinterpret_cast<const bf16x8*>(&Ahi[row1 * AST + koff]);
                const bf16x8 aL1 = *reinterpret_cast<const bf16x8*>(&Alo[row1 * AST + koff]);
                #pragma unroll
                for (int nt = 0; nt < 3; ++nt) {
                    acc[0][nt] = __builtin_amdgcn_mfma_f32_16x16x32_bf16(aH0, BH[nt][c], acc[0][nt], 0, 0, 0);
                    acc[1][nt] = __builtin_amdgcn_mfma_f32_16x16x32_bf16(aH1, BH[nt][c], acc[1][nt], 0, 0, 0);
                    acc[0][nt] = __builtin_amdgcn_mfma_f32_16x16x32_bf16(aL0, BH[nt][c], acc[0][nt], 0, 0, 0);
                    acc[1][nt] = __builtin_amdgcn_mfma_f32_16x16x32_bf16(aL1, BH[nt][c], acc[1][nt], 0, 0, 0);
                    acc[0][nt] = __builtin_amdgcn_mfma_f32_16x16x32_bf16(aH0, BL[nt][c], acc[0][nt], 0, 0, 0);
                    acc[1][nt] = __builtin_amdgcn_mfma_f32_16x16x32_bf16(aH1, BL[nt][c], acc[1][nt], 0, 0, 0);
                }
            }

            // epilogue: bias + SiLU + dot(W2) + 16-lane reduce
            #pragma unroll
            for (int s = 0; s < 2; ++s) {
                float p[4] = {0.f, 0.f, 0.f, 0.f};
                #pragma unroll
                for (int nt = 0; nt < 3; ++nt) {
                    #pragma unroll
                    for (int q = 0; q < 4; ++q) {
                        const float h = acc[s][nt][q] + b1v[nt];
                        p[q] = fmaf(h * fsigmoid(h), w2v[nt], p[q]);
                    }
                }
                #pragma unroll
                for (int m = 1; m <= 8; m <<= 1) {
                    #pragma unroll
                    for (int q = 0; q < 4; ++q) p[q] += __shfl_xor(p[q], m, 64);
                }
                if (lr == 0) {
                    const int rbase = (mp * 2 + s) * 16 + lq * 4;
                    #pragma unroll
                    for (int q = 0; q < 4; ++q) s_red[wave][rbase + q] = p[q];
                }
            }
        }
        __syncthreads();

        // finalize: att out + coordinate atomics (contiguous-lane pattern)
        if (tid < rows) {
            const int e = e0 + tid;
            const float att = fsigmoid(s_red[0][tid] + s_red[1][tid] + ba2v);
            const float phx = s_red[2][tid] + s_red[3][tid] + bx2v;
            out_att[e] = att;
            const int rcv = edge_idx[e];
            const int snd = edge_idx[E + e];
            const float dx = coords[snd * 3 + 0] - coords[rcv * 3 + 0];
            const float dy = coords[snd * 3 + 1] - coords[rcv * 3 + 1];
            const float dz = coords[snd * 3 + 2] - coords[rcv * 3 + 2];
            const float nr = sqrtf(dx * dx + dy * dy + dz * dz);
            const float f  = phx / (nr + 1.0f);
            atomicAdd(&out_coords[rcv * 3 + 0], dx * f);
            atomicAdd(&out_coords[rcv * 3 + 1], dy * f);
            atomicAdd(&out_coords[rcv * 3 + 2], dz * f);
        }
    }
}

// ---------------------------------------------------------------------------
// Gather kernel: m_acc[n] = sum over CSR bucket of att[e] * m_ji[e].
// Writes EVERY row densely (empty buckets -> zeros), so no memset needed.
// ---------------------------------------------------------------------------
__global__ __launch_bounds__(NT, 8)
void gather_kernel(const float* __restrict__ m_ji,
                   const float* __restrict__ att,
                   const int*   __restrict__ offsets,
                   const int*   __restrict__ eperm,
                   float* __restrict__ m_acc,
                   int N)
{
    const int lane = threadIdx.x & 63;
    const int wid  = (blockIdx.x * blockDim.x + threadIdx.x) >> 6;
    const int nw   = (gridDim.x * blockDim.x) >> 6;
    const int c2   = lane * 2;

    for (int n = wid; n < N; n += nw) {
        const int beg = offsets[n];
        const int end = offsets[n + 1];
        float ax = 0.f, ay = 0.f;
        for (int pos = beg; pos < end; ++pos) {
            const int e = eperm[pos];
            const float a = att[e];
            if (lane < 48) {
                const float2 v = *reinterpret_cast<const float2*>(&m_ji[(size_t)e * TC + c2]);
                ax = fmaf(a, v.x, ax);
                ay = fmaf(a, v.y, ay);
            }
        }
        if (lane < 48) {
            float2 o; o.x = ax; o.y = ay;
            *reinterpret_cast<float2*>(&m_acc[(size_t)n * TC + c2]) = o;
        }
    }
}

// ---------------------------------------------------------------------------
// Node kernel (MFMA split-bf16): X=[node_feats|m_acc] (K=192) -> SiLU -> K=96
// -> +bn2 +residual. 4 waves x 16 rows = 64 nodes/block. A-frags straight
// from global (8-elem chunks never cross the 96-col seam); B-frags from
// wprep-packed arrays (L2-resident, one dwordx4/lane). H staged per-wave in
// fp32 LDS (stride 100 -> <=2-way bank aliasing, free).
// A/B/k mappings identical to the HW-verified edge kernel.
// ---------------------------------------------------------------------------
__global__ __launch_bounds__(NT, 4)
void node_kernel(const float* __restrict__ node_feats,
                 const float* __restrict__ m_acc,
                 const __bf16* __restrict__ B1H, const __bf16* __restrict__ B1L,
                 const __bf16* __restrict__ B2H, const __bf16* __restrict__ B2L,
                 const float* __restrict__ bn1, const float* __restrict__ bn2,
                 float* __restrict__ out_nf, int N)
{
    __shared__ float Hld[4][16 * HLD];

    const int tid  = threadIdx.x;
    const int lane = tid & 63;
    const int wave = tid >> 6;
    const int lr   = lane & 15;
    const int lq   = lane >> 4;

    const int rowA = blockIdx.x * 64 + wave * 16 + lr;
    const int rA   = (rowA < N) ? rowA : (N - 1);

    // ---- GEMM1: X[64,192] @ Wn1[192,96], split-bf16 (hh+lh+hl) ----
    f32x4 acc[6];
    #pragma unroll
    for (int nt = 0; nt < 6; ++nt) acc[nt] = (f32x4){0.f, 0.f, 0.f, 0.f};

    #pragma unroll
    for (int c = 0; c < 6; ++c) {
        const int k0 = c * 32 + lq * 8;
        const float* src = (k0 < TC) ? (node_feats + (size_t)rA * TC + k0)
                                     : (m_acc + (size_t)rA * TC + (k0 - TC));
        const float4 v0 = *reinterpret_cast<const float4*>(src);
        const float4 v1 = *reinterpret_cast<const float4*>(src + 4);
        const float vv[8] = {v0.x, v0.y, v0.z, v0.w, v1.x, v1.y, v1.z, v1.w};
        bf16x8 aH, aL;
        #pragma unroll
        for (int j = 0; j < 8; ++j) {
            const __bf16 h = (__bf16)vv[j];
            aH[j] = h;
            aL[j] = (__bf16)(vv[j] - (float)h);
        }
        #pragma unroll
        for (int nt = 0; nt < 6; ++nt) {
            const size_t bi = ((size_t)(nt * 6 + c) * 64 + lane) * 8;
            const bf16x8 bH = *reinterpret_cast<const bf16x8*>(&B1H[bi]);
            const bf16x8 bL = *reinterpret_cast<const bf16x8*>(&B1L[bi]);
            acc[nt] = __builtin_amdgcn_mfma_f32_16x16x32_bf16(aH, bH, acc[nt], 0, 0, 0);
            acc[nt] = __builtin_amdgcn_mfma_f32_16x16x32_bf16(aL, bH, acc[nt], 0, 0, 0);
            acc[nt] = __builtin_amdgcn_mfma_f32_16x16x32_bf16(aH, bL, acc[nt], 0, 0, 0);
        }
    }

    // SiLU + bn1 -> per-wave H tile (C/D layout: row = lq*4+q, col = nt*16+lr)
    #pragma unroll
    for (int nt = 0; nt < 6; ++nt) {
        const float b = bn1[nt * 16 + lr];
        #pragma unroll
        for (int q = 0; q < 4; ++q) {
            const float h = acc[nt][q] + b;
            Hld[wave][(lq * 4 + q) * HLD + nt * 16 + lr] = h * fsigmoid(h);
        }
    }
    __syncthreads();

    // ---- GEMM2: H[64,96] @ Wn2[96,96], split-bf16 ----
    f32x4 acc2[6];
    #pragma unroll
    for (int nt = 0; nt < 6; ++nt) acc2[nt] = (f32x4){0.f, 0.f, 0.f, 0.f};

    #pragma unroll
    for (int c = 0; c < 3; ++c) {
        const int k0 = c * 32 + lq * 8;
        const float* hp = &Hld[wave][lr * HLD + k0];
        const float4 v0 = *reinterpret_cast<const float4*>(hp);
        const float4 v1 = *reinterpret_cast<const float4*>(hp + 4);
        const float vv[8] = {v0.x, v0.y, v0.z, v0.w, v1.x, v1.y, v1.z, v1.w};
        bf16x8 aH, aL;
        #pragma unroll
        for (int j = 0; j < 8; ++j) {
            const __bf16 h = (__bf16)vv[j];
            aH[j] = h;
            aL[j] = (__bf16)(vv[j] - (float)h);
        }
        #pragma unroll
        for (int nt = 0; nt < 6; ++nt) {
            const size_t bi = ((size_t)(nt * 3 + c) * 64 + lane) * 8;
            const bf16x8 bH = *reinterpret_cast<const bf16x8*>(&B2H[bi]);
            const bf16x8 bL = *reinterpret_cast<const bf16x8*>(&B2L[bi]);
            acc2[nt] = __builtin_amdgcn_mfma_f32_16x16x32_bf16(aH, bH, acc2[nt], 0, 0, 0);
            acc2[nt] = __builtin_amdgcn_mfma_f32_16x16x32_bf16(aL, bH, acc2[nt], 0, 0, 0);
            acc2[nt] = __builtin_amdgcn_mfma_f32_16x16x32_bf16(aH, bL, acc2[nt], 0, 0, 0);
        }
    }

    // epilogue: + bn2 + residual, predicated store
    #pragma unroll
    for (int q = 0; q < 4; ++q) {
        const int row = blockIdx.x * 64 + wave * 16 + lq * 4 + q;
        if (row < N) {
            #pragma unroll
            for (int nt = 0; nt < 6; ++nt) {
                const int col = nt * 16 + lr;
                out_nf[(size_t)row * TC + col] =
                    acc2[nt][q] + bn2[col] + node_feats[(size_t)row * TC + col];
            }
        }
    }
}

extern "C" void kernel_launch(void* const* d_in, const int* in_sizes, int n_in,
                              void* d_out, int out_size, void* d_ws, size_t ws_size,
                              hipStream_t stream)
{
    const float* node_feats = (const float*)d_in[0];
    const float* coords     = (const float*)d_in[1];
    const float* m_ji       = (const float*)d_in[2];
    const int*   edge_idx   = (const int*)  d_in[3];
    const float* Wn1 = (const float*)d_in[4];
    const float* bn1 = (const float*)d_in[5];
    const float* Wn2 = (const float*)d_in[6];
    const float* bn2 = (const float*)d_in[7];
    const float* Wa1 = (const float*)d_in[8];
    const float* ba1 = (const float*)d_in[9];
    const float* Wa2 = (const float*)d_in[10];
    const float* ba2 = (const float*)d_in[11];
    const float* Wx1 = (const float*)d_in[12];
    const float* bx1 = (const float*)d_in[13];
    const float* Wx2 = (const float*)d_in[14];
    const float* bx2 = (const float*)d_in[15];

    const int N = in_sizes[0] / TC;
    const int E = in_sizes[2] / TC;

    float* out_nf     = (float*)d_out;
    float* out_coords = out_nf + (size_t)N * TC;
    float* out_att    = out_coords + (size_t)N * 3;

    // workspace layout (256B-aligned slots)
    char* w = (char*)d_ws;
    float* m_acc  = (float*)w;   w += (((size_t)N * TC * 4) + 255) / 256 * 256;
    int* eperm    = (int*)w;     w += (((size_t)E * 4) + 255) / 256 * 256;
    int* count    = (int*)w;     w += (((size_t)N * 4) + 255) / 256 * 256;
    int* cursor   = (int*)w;     w += (((size_t)N * 4) + 255) / 256 * 256;
    int* offsets  = (int*)w;     w += (((size_t)(N + 1) * 4) + 255) / 256 * 256;
    __bf16* B1H   = (__bf16*)w;  w += ((36 * 64 * 8 * 2) + 255) / 256 * 256;
    __bf16* B1L   = (__bf16*)w;  w += ((36 * 64 * 8 * 2) + 255) / 256 * 256;
    __bf16* B2H   = (__bf16*)w;  w += ((18 * 64 * 8 * 2) + 255) / 256 * 256;
    __bf16* B2L   = (__bf16*)w;  w += ((18 * 64 * 8 * 2) + 255) / 256 * 256;

    // CSR build + weight prep
    hipMemsetAsync(count, 0, (size_t)N * sizeof(int), stream);
    hist_kernel<<<(E + NT - 1) / NT, NT, 0, stream>>>(edge_idx, count, E);
    scan_kernel<<<1, 1024, 0, stream>>>(count, offsets, cursor, N, E);
    fill_kernel<<<(E + NT - 1) / NT, NT, 0, stream>>>(edge_idx, cursor, eperm, E);
    wprep_kernel<<<(54 * 64 + NT - 1) / NT, NT, 0, stream>>>(Wn1, Wn2, B1H, B1L, B2H, B2L);

    // seed output coords
    hipMemcpyAsync(out_coords, coords, (size_t)N * 3 * sizeof(float),
                   hipMemcpyDeviceToDevice, stream);

    // edge MFMA: att + coord deltas
    const int ntiles = (E + EBM - 1) / EBM;
    edge_kernel<<<1024, NT, 0, stream>>>(
        m_ji, edge_idx, coords,
        Wa1, ba1, Wa2, ba2, Wx1, bx1, Wx2, bx2,
        out_coords, out_att, E, ntiles);

    // message gather
    gather_kernel<<<2048, NT, 0, stream>>>(m_ji, out_att, offsets, eperm, m_acc, N);

    // node MLP (MFMA)
    node_kernel<<<(N + 63) / 64, NT, 0, stream>>>(
        node_feats, m_acc, B1H, B1L, B2H, B2L, bn1, bn2, out_nf, N);
}